// Round 14
// baseline (150.688 us; speedup 1.0000x reference)
//
#include <hip/hip_runtime.h>

// MiniSTU: out[b,l,o] = sum_k sum_{s<=l} phi[l-s,k]*(x@Mp[k])[o] + (-1)^(l-s)-weighted Mm term
// Stage 1: Z[b][kk][o][s] gl16 counted-vmcnt GEMM, 32-K chunks, 40KB LDS (4 blocks/CU).
// Stage 2: 128l x 256o tile, 4 waves of 128lx64o (acc 8x4), A 2-buf + Z[256] 3-buf
//          (128KB LDS, 1 block/CU), r12 slot skeleton, counted vmcnt(8). bf16 partial.

#define ZB_ 12582912  // Z elems per batch (48*256*1024)

typedef __attribute__((ext_vector_type(8))) short bf16x8;
typedef __attribute__((ext_vector_type(4))) float f32x4;

__device__ inline unsigned short f2bf(float f) {
    unsigned u = __float_as_uint(f);
    u += 0x7FFFu + ((u >> 16) & 1u);   // RNE
    return (unsigned short)(u >> 16);
}

__device__ inline float bf2f(unsigned short s) {
    unsigned u = ((unsigned)s) << 16;
    return __uint_as_float(u);
}

__device__ inline void gl16(const unsigned short* g, unsigned short* l) {
    __builtin_amdgcn_global_load_lds((const __attribute__((address_space(1))) void*)g,
                                     (__attribute__((address_space(3))) void*)l, 16, 0, 0);
}

// ---- merged prep: [0,1024) prep_x | [1024,1792) prep_toep | [1792,4864) transpose_M
__global__ __launch_bounds__(256) void k_prep_all(const float* __restrict__ x,
                                                  const float* __restrict__ phi,
                                                  const float* __restrict__ Mp,
                                                  const float* __restrict__ Mm,
                                                  unsigned short* __restrict__ xb,
                                                  unsigned short* __restrict__ ToepA,
                                                  unsigned short* __restrict__ MbT) {
    __shared__ float tile[32][33];
    int bid = blockIdx.x, tid = threadIdx.x;
    if (bid < 1024) {
        // x (f32) -> xb (bf16), i pre-swizzled within 32-chunks by ((s>>1)&3)<<3
        int i = (bid * 256 + tid) * 4;
        float4 v = *(const float4*)(x + i);
        ushort4 o;
        o.x = f2bf(v.x); o.y = f2bf(v.y); o.z = f2bf(v.z); o.w = f2bf(v.w);
        int row = i >> 8, col = i & 255;
        int dst = (row << 8) | (col & 224) | ((col & 31) ^ (((row >> 1) & 3) << 3));
        *(ushort4*)(xb + dst) = o;
    } else if (bid < 1792) {
        // ToepA[kk][didx][i][j'] = sgn*phi[(didx-1)*64+i-j][k], j' = j ^ ((i&7)<<3)
        int r = bid - 1024;
        int kk = r >> 4;
        int dm = (r & 15) - 1;
        int k = (kk < 24) ? kk : kk - 24;
        int i = tid >> 1, j0 = (tid & 1) * 32;
        unsigned short* dst = ToepA + ((size_t)kk * 16 + (dm + 1)) * 8192 + i * 64;
        int sw = (i & 7) << 3;
#pragma unroll
        for (int q = 0; q < 8; ++q) {
            int j = j0 + q * 4;
            unsigned short e[4];
#pragma unroll
            for (int ee = 0; ee < 4; ++ee) {
                int t = dm * 64 + i - (j + ee);
                float v = 0.f;
                if (t >= 0 && t < 1024) {
                    v = phi[t * 24 + k];
                    if (kk >= 24 && (t & 1)) v = -v;
                }
                e[ee] = f2bf(v);
            }
            ushort4 ov; ov.x = e[0]; ov.y = e[1]; ov.z = e[2]; ov.w = e[3];
            *(ushort4*)(dst + (j ^ sw)) = ov;
        }
    } else {
        // MbT[kk][o][i'] = M(kk)[i][o], i pre-swizzled within 32 by ((o>>1)&3)<<3
        int flat = bid - 1792;
        int kk = flat >> 6, rr = flat & 63;
        int i0 = (rr >> 3) * 32, o0 = (rr & 7) * 32;
        int tx = tid & 31, ty = tid >> 5;
        const float* src = ((kk < 24) ? Mp : Mm) + (size_t)((kk < 24) ? kk : kk - 24) * 65536;
        for (int j = 0; j < 4; ++j)
            tile[ty + j * 8][tx] = src[(i0 + ty + j * 8) * 256 + o0 + tx];
        __syncthreads();
        for (int j = 0; j < 4; ++j) {
            int orow = o0 + ty + j * 8, i = i0 + tx;
            int ic = (i & 224) | ((i & 31) ^ (((orow >> 1) & 3) << 3));
            MbT[(size_t)kk * 65536 + orow * 256 + ic] = f2bf(tile[tx][ty + j * 8]);
        }
    }
}

// ---- stage 1: work (8 m-tiles, 96 = 48kk x 2 o-halves, g batches), 256 thr ---
// 32-K chunks x8, Ab 2-buf 1-ahead + Bb 3-buf 2-ahead (40KB), 4 blocks/CU.
__global__ __launch_bounds__(256, 4) void k_stage1(const unsigned short* __restrict__ xb0,
                                                   const unsigned short* __restrict__ MbT,
                                                   unsigned short* __restrict__ Z) {
    __shared__ unsigned short Ab[2][4096];
    __shared__ unsigned short Bb[3][4096];
    int tid = threadIdx.x, lane = tid & 63, w = tid >> 6;
    int wm = w >> 1, wn = w & 1;

    // XCD-chunked bijective remap
    int nwg = 768 * gridDim.z;
    int orig = blockIdx.x + blockIdx.y * 8 + blockIdx.z * 768;
    int wg = (orig & 7) * (nwg >> 3) + (orig >> 3);
    int m0 = (wg & 7) * 128;
    int rem = wg >> 3;
    int yy = rem % 96;
    int b  = rem / 96;
    int kk = yy >> 1;
    int o0 = (yy & 1) * 128;

    const unsigned short* xb_b = xb0 + (size_t)b * 262144;
    unsigned short* Zb = Z + (size_t)b * ZB_;
    const unsigned short* Bsrc = MbT + (size_t)kk * 65536;
    int l16 = lane & 15, kofs = (lane >> 4) * 8;
    int sw32 = ((l16 >> 1) & 3) << 3;
    int r4l = lane >> 2, c4 = (lane & 3) * 8;

    int arow[2], brow[2], lofs[2];
#pragma unroll
    for (int q = 0; q < 2; ++q) {
        int rr = q * 64 + w * 16 + r4l;
        arow[q] = (m0 + rr) * 256 + c4;
        brow[q] = (o0 + rr) * 256 + c4;
        lofs[q] = q * 2048 + w * 512;
    }

    f32x4 acc[4][4];
    for (int i = 0; i < 4; ++i)
        for (int j = 0; j < 4; ++j) {
            acc[i][j][0] = 0.f; acc[i][j][1] = 0.f; acc[i][j][2] = 0.f; acc[i][j][3] = 0.f;
        }

    auto stageA = [&](int bi, int ko) {
#pragma unroll
        for (int q = 0; q < 2; ++q) gl16(xb_b + arow[q] + ko * 32, &Ab[bi][0] + lofs[q]);
    };
    auto stageB = [&](int bi, int ko) {
#pragma unroll
        for (int q = 0; q < 2; ++q) gl16(Bsrc + brow[q] + ko * 32, &Bb[bi][0] + lofs[q]);
    };

    stageA(0, 0); stageB(0, 0); stageB(1, 1);   // 6 loads in flight

    for (int ko = 0; ko < 8; ++ko) {
        if (ko < 7) { asm volatile("s_waitcnt vmcnt(2)" ::: "memory"); }
        else        { asm volatile("s_waitcnt vmcnt(0)" ::: "memory"); }
        __builtin_amdgcn_sched_barrier(0);
        __builtin_amdgcn_s_barrier();
        __builtin_amdgcn_sched_barrier(0);
        if (ko < 7) stageA((ko + 1) & 1, ko + 1);
        if (ko < 6) stageB((ko + 2) % 3, ko + 2);

        const unsigned short* Abase = &Ab[ko & 1][0];
        const unsigned short* Bbase = &Bb[ko % 3][0];
        int koX = kofs ^ sw32;
        bf16x8 af[4], bfv[4];
#pragma unroll
        for (int mi = 0; mi < 4; ++mi)
            af[mi] = *(const bf16x8*)(Abase + (wm * 64 + mi * 16 + l16) * 32 + koX);
#pragma unroll
        for (int ni = 0; ni < 4; ++ni)
            bfv[ni] = *(const bf16x8*)(Bbase + (wn * 64 + ni * 16 + l16) * 32 + koX);
        __builtin_amdgcn_s_setprio(1);
#pragma unroll
        for (int mi = 0; mi < 4; ++mi)
#pragma unroll
            for (int ni = 0; ni < 4; ++ni)
                acc[mi][ni] = __builtin_amdgcn_mfma_f32_16x16x32_bf16(af[mi], bfv[ni], acc[mi][ni], 0, 0, 0);
        __builtin_amdgcn_s_setprio(0);
    }

    // store Z with s pre-swizzled by (o&7)<<3 within 64-chunks (stage2's pair)
    int r4 = (lane >> 4) * 4;
    for (int mi = 0; mi < 4; ++mi) {
        int sbase = m0 + wm * 64 + mi * 16 + r4;
        for (int ni = 0; ni < 4; ++ni) {
            int o = o0 + wn * 64 + ni * 16 + l16;
            ushort4 pk;
            pk.x = f2bf(acc[mi][ni][0]); pk.y = f2bf(acc[mi][ni][1]);
            pk.z = f2bf(acc[mi][ni][2]); pk.w = f2bf(acc[mi][ni][3]);
            *(ushort4*)(Zb + (size_t)kk * 262144 + (size_t)o * 1024 + (sbase ^ ((o & 7) << 3))) = pk;
        }
    }
}

// ---- stage 2: grid (4 diag-pairs, g batches, kg), 256 thr (4 waves) ---------
// Tile 128l x 256o; wave w owns o in [w*64, w*64+64), full 128 l (acc 8x4).
// A 2-buf 1-ahead + Z 3-buf 2-ahead (128KB, 1 block/CU). Steady vmcnt(8).
__global__ __launch_bounds__(256, 1) void k_stage2(const unsigned short* __restrict__ Z,
                                                   const unsigned short* __restrict__ ToepA,
                                                   unsigned short* __restrict__ partial, int kkpg) {
    __shared__ unsigned short Abuf[2][8192];    // 2 x 16 KB
    __shared__ unsigned short Zbuf[3][16384];   // 3 x 32 KB  -> 128 KB total
    int tid = threadIdx.x, lane = tid & 63, w = tid >> 6;

    // XCD-chunked bijective remap (nwg = 4*g*kg, multiple of 8)
    int gy = gridDim.y, nwg = 4 * gy * gridDim.z;
    int orig = blockIdx.x + blockIdx.y * 4 + blockIdx.z * 4 * gy;
    int wg = (orig & 7) * (nwg >> 3) + (orig >> 3);
    int pr = wg & 3;
    int rem = wg >> 2;
    int b   = rem % gy;
    int kgi = rem / gy;
    int kk0 = kgi * kkpg;

    int l16 = lane & 15, kofs = (lane >> 4) * 8;
    int sw = (l16 & 7) << 3;

    const unsigned short* Zb = Z + (size_t)b * ZB_;
    unsigned short* pb = partial + ((size_t)b * gridDim.z + kgi) * 262144;

    // staging offsets: thread covers rows q*32 + (tid>>3), col-group (tid&7)*8
    int r0 = tid >> 3, cg = (tid & 7) * 8;
    int arow[4], lofsA[4];
#pragma unroll
    for (int q = 0; q < 4; ++q) {           // A: 128 rows x 64 cols
        arow[q]  = (q * 32 + r0) * 64 + cg;
        lofsA[q] = q * 2048 + (r0 * 64 + cg) - (r0 * 64 + cg) + (r0 * 64 + cg); // = q*2048 + r0*64+cg
    }
    int zrow[8], lofsZ[8];
#pragma unroll
    for (int q = 0; q < 8; ++q) {           // Z: 256 rows x 64 cols
        zrow[q]  = (q * 32 + r0) * 1024 + cg;
        lofsZ[q] = q * 2048 + r0 * 64 + cg;
    }

    for (int half = 0; half < 2; ++half) {
        int lb = half ? (7 - pr) : pr;
        int l0 = lb * 128;
        int nch = 2 * lb + 2;
        int total = kkpg * nch;   // >= 6 (kkpg>=3)

        f32x4 acc[8][4];
        for (int i = 0; i < 8; ++i)
            for (int j = 0; j < 4; ++j) {
                acc[i][j][0] = 0.f; acc[i][j][1] = 0.f; acc[i][j][2] = 0.f; acc[i][j][3] = 0.f;
            }

        __syncthreads();   // previous-half LDS readers done

        auto stageA = [&](int bi, int kka, int didx) {
            const unsigned short* gA = ToepA + ((size_t)kka * 16 + didx) * 8192;
#pragma unroll
            for (int q = 0; q < 4; ++q) gl16(gA + arow[q], &Abuf[bi][0] + lofsA[q]);
        };
        auto stageZ = [&](int bi, int kka, int s0) {
            const unsigned short* gZ = Zb + (size_t)kka * 262144 + s0;
#pragma unroll
            for (int q = 0; q < 8; ++q) gl16(gZ + zrow[q], &Zbuf[bi][0] + lofsZ[q]);
        };
        auto compute = [&](int ba, int bz) {
            const unsigned short* Abase = &Abuf[ba][0];
            const unsigned short* Zbase = &Zbuf[bz][0];
            __builtin_amdgcn_s_setprio(1);
#pragma unroll
            for (int ks = 0; ks < 2; ++ks) {
                int koX = (ks * 32 + kofs) ^ sw;
                bf16x8 af[8], bfv[4];
#pragma unroll
                for (int mi = 0; mi < 8; ++mi)
                    af[mi] = *(const bf16x8*)(Abase + (mi * 16 + l16) * 64 + koX);
#pragma unroll
                for (int ni = 0; ni < 4; ++ni)
                    bfv[ni] = *(const bf16x8*)(Zbase + (w * 64 + ni * 16 + l16) * 64 + koX);
#pragma unroll
                for (int mi = 0; mi < 8; ++mi)
#pragma unroll
                    for (int ni = 0; ni < 4; ++ni)
                        acc[mi][ni] = __builtin_amdgcn_mfma_f32_16x16x32_bf16(af[mi], bfv[ni], acc[mi][ni], 0, 0, 0);
            }
            __builtin_amdgcn_s_setprio(0);
        };

        // prologue: A(0), Z(0), Z(1)  -> per-thread outstanding: 4 + 8 + 8 = 20
        stageA(0, kk0, 2 * lb + 1);
        stageZ(0, kk0, 0);
        stageZ(1, kk0, 64);

        int scA = 1, kkA = 0;
        int scZ = 2, kkZ = 0;
        if (scZ == nch) { scZ = 0; kkZ = 1; }
        int jz = 2;

        for (int j = 0; j < total - 1; ++j) {
            asm volatile("s_waitcnt vmcnt(8)" ::: "memory");
            __builtin_amdgcn_sched_barrier(0);
            __builtin_amdgcn_s_barrier();
            __builtin_amdgcn_sched_barrier(0);
            stageA((j + 1) & 1, kk0 + kkA, 2 * lb - scA + 1);
            ++scA; if (scA == nch) { scA = 0; ++kkA; }
            if (jz < total) {
                stageZ(jz % 3, kk0 + kkZ, scZ * 64);
                ++scZ; if (scZ == nch) { scZ = 0; ++kkZ; }
                ++jz;
            }
            compute(j & 1, j % 3);
        }
        asm volatile("s_waitcnt vmcnt(0)" ::: "memory");
        __builtin_amdgcn_sched_barrier(0);
        __builtin_amdgcn_s_barrier();
        __builtin_amdgcn_sched_barrier(0);
        compute((total - 1) & 1, (total - 1) % 3);

        int r4 = (lane >> 4) * 4;
        for (int mi = 0; mi < 8; ++mi) {
            int l = l0 + mi * 16 + r4;
            for (int ni = 0; ni < 4; ++ni) {
                int o = w * 64 + ni * 16 + l16;
                unsigned short* dst = pb + (size_t)l * 256 + o;
                dst[0]   = f2bf(acc[mi][ni][0]);
                dst[256] = f2bf(acc[mi][ni][1]);
                dst[512] = f2bf(acc[mi][ni][2]);
                dst[768] = f2bf(acc[mi][ni][3]);
            }
        }
    }
}

// ---- reduce: out[b][l][o] = sum_kg partial[b][kg][l][o] (bf16 -> f32) --------
__global__ void k_reduce(const unsigned short* __restrict__ partial, float* __restrict__ outg, int kg) {
    const unsigned short* pb = partial + (size_t)blockIdx.y * kg * 262144;
    int i = (blockIdx.x * 256 + threadIdx.x) * 8;
    float s[8];
#pragma unroll
    for (int j = 0; j < 8; ++j) s[j] = 0.f;
    for (int kgi = 0; kgi < kg; ++kgi) {
        uint4 v = *(const uint4*)(pb + (size_t)kgi * 262144 + i);
        unsigned vv[4] = {v.x, v.y, v.z, v.w};
#pragma unroll
        for (int q = 0; q < 4; ++q) {
            s[q * 2]     += bf2f((unsigned short)(vv[q] & 0xFFFF));
            s[q * 2 + 1] += bf2f((unsigned short)(vv[q] >> 16));
        }
    }
    float4 o0, o1;
    o0.x = s[0]; o0.y = s[1]; o0.z = s[2]; o0.w = s[3];
    o1.x = s[4]; o1.y = s[5]; o1.z = s[6]; o1.w = s[7];
    float* dst = outg + (size_t)blockIdx.y * 262144 + i;
    *(float4*)(dst) = o0;
    *(float4*)(dst + 4) = o1;
}

extern "C" void kernel_launch(void* const* d_in, const int* in_sizes, int n_in,
                              void* d_out, int out_size, void* d_ws, size_t ws_size,
                              hipStream_t stream) {
    const float* x   = (const float*)d_in[0];   // [4,1024,256]
    const float* phi = (const float*)d_in[1];   // [1024,24]
    const float* Mp  = (const float*)d_in[2];   // [24,256,256]
    const float* Mm  = (const float*)d_in[3];   // [24,256,256]
    float* out = (float*)d_out;                 // [4,1024,256]

    char* ws = (char*)d_ws;
    unsigned short* xb    = (unsigned short*)(ws);             //  2,097,152 B
    unsigned short* MbT   = (unsigned short*)(ws + 2097152);   //  6,291,456 B
    unsigned short* ToepA = (unsigned short*)(ws + 8388608);   // 12,582,912 B
    unsigned short* Zbuf  = (unsigned short*)(ws + 20971520);  // g * 25,165,824 B
    const size_t fixed = 20971520;

    int g = 4, kg = 16;
    auto need = [&](int gg, int kk) {
        return fixed + (size_t)gg * 25165824 + (size_t)gg * (size_t)kk * 524288;
    };
    if (need(4, 16) > ws_size) {
        kg = 12;
        if (need(4, 12) > ws_size) {
            g = 2; kg = 16;
            if (need(2, 16) > ws_size) {
                kg = 12;
                if (need(2, 12) > ws_size) {
                    g = 1; kg = 16;
                    if (need(1, 16) > ws_size) {
                        kg = 12;
                        if (need(1, 12) > ws_size) kg = 6;
                    }
                }
            }
        }
    }
    unsigned short* partial = (unsigned short*)(ws + fixed + (size_t)g * 25165824);

    k_prep_all<<<dim3(4864), dim3(256), 0, stream>>>(x, phi, Mp, Mm, xb, ToepA, MbT);

    for (int b0 = 0; b0 < 4; b0 += g) {
        k_stage1<<<dim3(8, 96, g), dim3(256), 0, stream>>>(xb + (size_t)b0 * 262144, MbT, Zbuf);
        k_stage2<<<dim3(4, g, kg), dim3(256), 0, stream>>>(Zbuf, ToepA, partial, 48 / kg);
        k_reduce<<<dim3(128, g), dim3(256), 0, stream>>>(partial, out + (size_t)b0 * 262144, kg);
    }
}

// Round 15
// 134.117 us; speedup vs baseline: 1.1236x; 1.1236x over previous
//
#include <hip/hip_runtime.h>

// MiniSTU: out[b,l,o] = sum_k sum_{s<=l} phi[l-s,k]*(x@Mp[k])[o] + (-1)^(l-s)-weighted Mm term
// Stage 1: Z[b][kk][o][s] gl16 counted-vmcnt GEMM, 32-K chunks, 40KB LDS (4 blocks/CU).
// Stage 2: 128l x 128o Toeplitz GEMM, 32-wide s-chunks, A 2x8KB + Z 3x8KB (40KB LDS,
//          4 blocks/CU capacity, kg=24 -> 768 blocks = 3/CU), counted vmcnt(2).
// All swizzles 32-scope: col' = col ^ (((row>>1)&3)<<3), pre-swizzled global + XOR read.

#define ZB_ 12582912  // Z elems per batch (48*256*1024)

typedef __attribute__((ext_vector_type(8))) short bf16x8;
typedef __attribute__((ext_vector_type(4))) float f32x4;

__device__ inline unsigned short f2bf(float f) {
    unsigned u = __float_as_uint(f);
    u += 0x7FFFu + ((u >> 16) & 1u);   // RNE
    return (unsigned short)(u >> 16);
}

__device__ inline float bf2f(unsigned short s) {
    unsigned u = ((unsigned)s) << 16;
    return __uint_as_float(u);
}

__device__ inline void gl16(const unsigned short* g, unsigned short* l) {
    __builtin_amdgcn_global_load_lds((const __attribute__((address_space(1))) void*)g,
                                     (__attribute__((address_space(3))) void*)l, 16, 0, 0);
}

// ---- merged prep: [0,1024) prep_x | [1024,2560) prep_toep | [2560,5632) transpose_M
__global__ __launch_bounds__(256) void k_prep_all(const float* __restrict__ x,
                                                  const float* __restrict__ phi,
                                                  const float* __restrict__ Mp,
                                                  const float* __restrict__ Mm,
                                                  unsigned short* __restrict__ xb,
                                                  unsigned short* __restrict__ ToepA,
                                                  unsigned short* __restrict__ MbT) {
    __shared__ float tile[32][33];
    int bid = blockIdx.x, tid = threadIdx.x;
    if (bid < 1024) {
        // x (f32) -> xb (bf16), i pre-swizzled within 32-chunks by ((s>>1)&3)<<3
        int i = (bid * 256 + tid) * 4;
        float4 v = *(const float4*)(x + i);
        ushort4 o;
        o.x = f2bf(v.x); o.y = f2bf(v.y); o.z = f2bf(v.z); o.w = f2bf(v.w);
        int row = i >> 8, col = i & 255;
        int dst = (row << 8) | (col & 224) | ((col & 31) ^ (((row >> 1) & 3) << 3));
        *(ushort4*)(xb + dst) = o;
    } else if (bid < 2560) {
        // ToepA[kk][didx] 128x32 tiles: A[i][j] = P(32*(didx-3) + i - j), P(t)=sgn*phi[t][k]
        // col pre-swizzled: j' = j ^ (((i>>1)&3)<<3)
        int r = bid - 1024;
        int kk = r >> 5;
        int didx = r & 31;
        int d = 32 * didx - 96;
        int k = (kk < 24) ? kk : kk - 24;
        bool neg = kk >= 24;
        int i = tid >> 1, j0 = (tid & 1) * 16;
        unsigned short* dst = ToepA + ((size_t)kk * 32 + didx) * 4096 + i * 32;
        int sw = ((i >> 1) & 3) << 3;
#pragma unroll
        for (int q = 0; q < 4; ++q) {
            int j = j0 + q * 4;
            unsigned short e[4];
#pragma unroll
            for (int ee = 0; ee < 4; ++ee) {
                int t = d + i - (j + ee);
                float v = 0.f;
                if (t >= 0 && t < 1024) {
                    v = phi[t * 24 + k];
                    if (neg && (t & 1)) v = -v;
                }
                e[ee] = f2bf(v);
            }
            ushort4 ov; ov.x = e[0]; ov.y = e[1]; ov.z = e[2]; ov.w = e[3];
            *(ushort4*)(dst + (j ^ sw)) = ov;
        }
    } else {
        // MbT[kk][o][i'] = M(kk)[i][o], i pre-swizzled within 32 by ((o>>1)&3)<<3
        int flat = bid - 2560;
        int kk = flat >> 6, rr = flat & 63;
        int i0 = (rr >> 3) * 32, o0 = (rr & 7) * 32;
        int tx = tid & 31, ty = tid >> 5;
        const float* src = ((kk < 24) ? Mp : Mm) + (size_t)((kk < 24) ? kk : kk - 24) * 65536;
        for (int j = 0; j < 4; ++j)
            tile[ty + j * 8][tx] = src[(i0 + ty + j * 8) * 256 + o0 + tx];
        __syncthreads();
        for (int j = 0; j < 4; ++j) {
            int orow = o0 + ty + j * 8, i = i0 + tx;
            int ic = (i & 224) | ((i & 31) ^ (((orow >> 1) & 3) << 3));
            MbT[(size_t)kk * 65536 + orow * 256 + ic] = f2bf(tile[tx][ty + j * 8]);
        }
    }
}

// ---- stage 1: work (8 m-tiles, 96 = 48kk x 2 o-halves, g batches), 256 thr ---
// 32-K chunks x8, Ab 2-buf 1-ahead + Bb 3-buf 2-ahead (40KB), 4 blocks/CU.
__global__ __launch_bounds__(256, 4) void k_stage1(const unsigned short* __restrict__ xb0,
                                                   const unsigned short* __restrict__ MbT,
                                                   unsigned short* __restrict__ Z) {
    __shared__ unsigned short Ab[2][4096];
    __shared__ unsigned short Bb[3][4096];
    int tid = threadIdx.x, lane = tid & 63, w = tid >> 6;
    int wm = w >> 1, wn = w & 1;

    // XCD-chunked bijective remap
    int nwg = 768 * gridDim.z;
    int orig = blockIdx.x + blockIdx.y * 8 + blockIdx.z * 768;
    int wg = (orig & 7) * (nwg >> 3) + (orig >> 3);
    int m0 = (wg & 7) * 128;
    int rem = wg >> 3;
    int yy = rem % 96;
    int b  = rem / 96;
    int kk = yy >> 1;
    int o0 = (yy & 1) * 128;

    const unsigned short* xb_b = xb0 + (size_t)b * 262144;
    unsigned short* Zb = Z + (size_t)b * ZB_;
    const unsigned short* Bsrc = MbT + (size_t)kk * 65536;
    int l16 = lane & 15, kofs = (lane >> 4) * 8;
    int sw32 = ((l16 >> 1) & 3) << 3;
    int r4l = lane >> 2, c4 = (lane & 3) * 8;

    int arow[2], brow[2], lofs[2];
#pragma unroll
    for (int q = 0; q < 2; ++q) {
        int rr = q * 64 + w * 16 + r4l;
        arow[q] = (m0 + rr) * 256 + c4;
        brow[q] = (o0 + rr) * 256 + c4;
        lofs[q] = q * 2048 + w * 512;
    }

    f32x4 acc[4][4];
    for (int i = 0; i < 4; ++i)
        for (int j = 0; j < 4; ++j) {
            acc[i][j][0] = 0.f; acc[i][j][1] = 0.f; acc[i][j][2] = 0.f; acc[i][j][3] = 0.f;
        }

    auto stageA = [&](int bi, int ko) {
#pragma unroll
        for (int q = 0; q < 2; ++q) gl16(xb_b + arow[q] + ko * 32, &Ab[bi][0] + lofs[q]);
    };
    auto stageB = [&](int bi, int ko) {
#pragma unroll
        for (int q = 0; q < 2; ++q) gl16(Bsrc + brow[q] + ko * 32, &Bb[bi][0] + lofs[q]);
    };

    stageA(0, 0); stageB(0, 0); stageB(1, 1);   // 6 loads in flight

    for (int ko = 0; ko < 8; ++ko) {
        if (ko < 7) { asm volatile("s_waitcnt vmcnt(2)" ::: "memory"); }
        else        { asm volatile("s_waitcnt vmcnt(0)" ::: "memory"); }
        __builtin_amdgcn_sched_barrier(0);
        __builtin_amdgcn_s_barrier();
        __builtin_amdgcn_sched_barrier(0);
        if (ko < 7) stageA((ko + 1) & 1, ko + 1);
        if (ko < 6) stageB((ko + 2) % 3, ko + 2);

        const unsigned short* Abase = &Ab[ko & 1][0];
        const unsigned short* Bbase = &Bb[ko % 3][0];
        int koX = kofs ^ sw32;
        bf16x8 af[4], bfv[4];
#pragma unroll
        for (int mi = 0; mi < 4; ++mi)
            af[mi] = *(const bf16x8*)(Abase + (wm * 64 + mi * 16 + l16) * 32 + koX);
#pragma unroll
        for (int ni = 0; ni < 4; ++ni)
            bfv[ni] = *(const bf16x8*)(Bbase + (wn * 64 + ni * 16 + l16) * 32 + koX);
        __builtin_amdgcn_s_setprio(1);
#pragma unroll
        for (int mi = 0; mi < 4; ++mi)
#pragma unroll
            for (int ni = 0; ni < 4; ++ni)
                acc[mi][ni] = __builtin_amdgcn_mfma_f32_16x16x32_bf16(af[mi], bfv[ni], acc[mi][ni], 0, 0, 0);
        __builtin_amdgcn_s_setprio(0);
    }

    // store Z with s pre-swizzled within 32-chunks by ((o>>1)&3)<<3 (stage2's pair)
    int r4 = (lane >> 4) * 4;
    int swo = 0;
    for (int mi = 0; mi < 4; ++mi) {
        int sbase = m0 + wm * 64 + mi * 16 + r4;
        for (int ni = 0; ni < 4; ++ni) {
            int o = o0 + wn * 64 + ni * 16 + l16;
            swo = ((o >> 1) & 3) << 3;
            int sidx = (sbase & ~31) | ((sbase & 31) ^ swo);
            ushort4 pk;
            pk.x = f2bf(acc[mi][ni][0]); pk.y = f2bf(acc[mi][ni][1]);
            pk.z = f2bf(acc[mi][ni][2]); pk.w = f2bf(acc[mi][ni][3]);
            *(ushort4*)(Zb + (size_t)kk * 262144 + (size_t)o * 1024 + sidx) = pk;
        }
    }
}

// ---- stage 2: grid (4 diag-pairs, 2 o-tiles x g batches, kg), 256 thr --------
// 32-wide s-chunks: A 2x8KB 1-ahead + Z 3x8KB 2-ahead (40KB, 4 blocks/CU).
__global__ __launch_bounds__(256, 4) void k_stage2(const unsigned short* __restrict__ Z,
                                                   const unsigned short* __restrict__ ToepA,
                                                   unsigned short* __restrict__ partial, int kkpg) {
    __shared__ unsigned short Abuf[2][4096];
    __shared__ unsigned short Zbuf[3][4096];
    int tid = threadIdx.x, lane = tid & 63, w = tid >> 6;
    int wm = w >> 1, wn = w & 1;

    // XCD-chunked bijective remap (nwg % 8 == 0 always here)
    int gy = gridDim.y, nwg = 4 * gy * gridDim.z;
    int orig = blockIdx.x + blockIdx.y * 4 + blockIdx.z * 4 * gy;
    int wg = (orig & 7) * (nwg >> 3) + (orig >> 3);
    int pr = wg & 3;
    int yy = (wg >> 2) % gy;
    int zz = (wg >> 2) / gy;
    int o0 = (yy & 1) * 128;
    int b  = yy >> 1;
    int kgi = zz;
    int kk0 = kgi * kkpg;

    int l16 = lane & 15, kofs = (lane >> 4) * 8;
    int koX = kofs ^ (((l16 >> 1) & 3) << 3);

    const unsigned short* Zb = Z + (size_t)b * ZB_;
    unsigned short* pb = partial + ((size_t)b * gridDim.z + kgi) * 262144;

    // staging: thread's 16B slice q: A src = q*2048 + tid*8 (contiguous);
    // Z src row = q*64 + (tid>>2), col (tid&3)*8; LDS dest = q*2048 + tid*8 (lane-linear)
    int t8 = tid * 8;
    int zr = (tid >> 2) * 1024 + (tid & 3) * 8;

    for (int half = 0; half < 2; ++half) {
        int lb = half ? (7 - pr) : pr;
        int l0 = lb * 128;
        int nch = 4 * lb + 4;
        int total = kkpg * nch;   // >= 8

        f32x4 acc[4][4];
        for (int i = 0; i < 4; ++i)
            for (int j = 0; j < 4; ++j) {
                acc[i][j][0] = 0.f; acc[i][j][1] = 0.f; acc[i][j][2] = 0.f; acc[i][j][3] = 0.f;
            }

        __syncthreads();   // previous-half LDS readers done

        auto stageA = [&](int bi, int kka, int sc) {
            const unsigned short* gA = ToepA + ((size_t)kka * 32 + (4 * lb - sc + 3)) * 4096;
            gl16(gA + t8, &Abuf[bi][0] + t8);
            gl16(gA + 2048 + t8, &Abuf[bi][0] + 2048 + t8);
        };
        auto stageZ = [&](int bi, int kka, int sc) {
            const unsigned short* gZ = Zb + (size_t)kka * 262144 + (size_t)o0 * 1024 + sc * 32;
            gl16(gZ + zr, &Zbuf[bi][0] + t8);
            gl16(gZ + 65536 + zr, &Zbuf[bi][0] + 2048 + t8);
        };
        auto compute = [&](int ba, int bz) {
            const unsigned short* Abase = &Abuf[ba][0];
            const unsigned short* Zbase = &Zbuf[bz][0];
            bf16x8 af[4], bfv[4];
#pragma unroll
            for (int mi = 0; mi < 4; ++mi)
                af[mi] = *(const bf16x8*)(Abase + (wm * 64 + mi * 16 + l16) * 32 + koX);
#pragma unroll
            for (int ni = 0; ni < 4; ++ni)
                bfv[ni] = *(const bf16x8*)(Zbase + (wn * 64 + ni * 16 + l16) * 32 + koX);
            __builtin_amdgcn_s_setprio(1);
#pragma unroll
            for (int mi = 0; mi < 4; ++mi)
#pragma unroll
                for (int ni = 0; ni < 4; ++ni)
                    acc[mi][ni] = __builtin_amdgcn_mfma_f32_16x16x32_bf16(af[mi], bfv[ni], acc[mi][ni], 0, 0, 0);
            __builtin_amdgcn_s_setprio(0);
        };

        // prologue: A(0), Z(0), Z(1)  -> 6 loads in flight
        stageA(0, kk0, 0);
        stageZ(0, kk0, 0);
        stageZ(1, kk0, 1);

        int scA = 1, kkA = 0;
        int scZ = 2, kkZ = 0;
        int jz = 2;

        for (int j = 0; j < total - 1; ++j) {
            asm volatile("s_waitcnt vmcnt(2)" ::: "memory");
            __builtin_amdgcn_sched_barrier(0);
            __builtin_amdgcn_s_barrier();
            __builtin_amdgcn_sched_barrier(0);
            stageA((j + 1) & 1, kk0 + kkA, scA);
            ++scA; if (scA == nch) { scA = 0; ++kkA; }
            if (jz < total) {
                stageZ(jz % 3, kk0 + kkZ, scZ);
                ++scZ; if (scZ == nch) { scZ = 0; ++kkZ; }
                ++jz;
            }
            compute(j & 1, j % 3);
        }
        asm volatile("s_waitcnt vmcnt(0)" ::: "memory");
        __builtin_amdgcn_sched_barrier(0);
        __builtin_amdgcn_s_barrier();
        __builtin_amdgcn_sched_barrier(0);
        compute((total - 1) & 1, (total - 1) % 3);

        int r4 = (lane >> 4) * 4;
        for (int mi = 0; mi < 4; ++mi) {
            int l = l0 + wm * 64 + mi * 16 + r4;
            for (int ni = 0; ni < 4; ++ni) {
                int o = o0 + wn * 64 + ni * 16 + l16;
                unsigned short* dst = pb + (size_t)l * 256 + o;
                dst[0]   = f2bf(acc[mi][ni][0]);
                dst[256] = f2bf(acc[mi][ni][1]);
                dst[512] = f2bf(acc[mi][ni][2]);
                dst[768] = f2bf(acc[mi][ni][3]);
            }
        }
    }
}

// ---- reduce: out[b][l][o] = sum_kg partial[b][kg][l][o] (bf16 -> f32) --------
__global__ void k_reduce(const unsigned short* __restrict__ partial, float* __restrict__ outg, int kg) {
    const unsigned short* pb = partial + (size_t)blockIdx.y * kg * 262144;
    int i = (blockIdx.x * 256 + threadIdx.x) * 8;
    float s[8];
#pragma unroll
    for (int j = 0; j < 8; ++j) s[j] = 0.f;
    for (int kgi = 0; kgi < kg; ++kgi) {
        uint4 v = *(const uint4*)(pb + (size_t)kgi * 262144 + i);
        unsigned vv[4] = {v.x, v.y, v.z, v.w};
#pragma unroll
        for (int q = 0; q < 4; ++q) {
            s[q * 2]     += bf2f((unsigned short)(vv[q] & 0xFFFF));
            s[q * 2 + 1] += bf2f((unsigned short)(vv[q] >> 16));
        }
    }
    float4 o0, o1;
    o0.x = s[0]; o0.y = s[1]; o0.z = s[2]; o0.w = s[3];
    o1.x = s[4]; o1.y = s[5]; o1.z = s[6]; o1.w = s[7];
    float* dst = outg + (size_t)blockIdx.y * 262144 + i;
    *(float4*)(dst) = o0;
    *(float4*)(dst + 4) = o1;
}

extern "C" void kernel_launch(void* const* d_in, const int* in_sizes, int n_in,
                              void* d_out, int out_size, void* d_ws, size_t ws_size,
                              hipStream_t stream) {
    const float* x   = (const float*)d_in[0];   // [4,1024,256]
    const float* phi = (const float*)d_in[1];   // [1024,24]
    const float* Mp  = (const float*)d_in[2];   // [24,256,256]
    const float* Mm  = (const float*)d_in[3];   // [24,256,256]
    float* out = (float*)d_out;                 // [4,1024,256]

    char* ws = (char*)d_ws;
    unsigned short* xb    = (unsigned short*)(ws);             //  2,097,152 B
    unsigned short* MbT   = (unsigned short*)(ws + 2097152);   //  6,291,456 B
    unsigned short* ToepA = (unsigned short*)(ws + 8388608);   // 12,582,912 B (48*32 tiles 128x32)
    unsigned short* Zbuf  = (unsigned short*)(ws + 20971520);  // g * 25,165,824 B
    const size_t fixed = 20971520;

    // prefer g=4, kg=24 (768 blocks -> 3/CU at 4-capacity); ws >= 188.7MB proven (r5-r8).
    int g = 4, kg = 24;
    auto need = [&](int gg, int kk) {
        return fixed + (size_t)gg * 25165824 + (size_t)gg * (size_t)kk * 524288;
    };
    if (need(4, 24) > ws_size) {
        kg = 16;
        if (need(4, 16) > ws_size) {
            kg = 12;
            if (need(4, 12) > ws_size) {
                g = 2; kg = 24;
                if (need(2, 24) > ws_size) {
                    kg = 12;
                    if (need(2, 12) > ws_size) {
                        g = 1; kg = 24;
                        if (need(1, 24) > ws_size) {
                            kg = 12;
                            if (need(1, 12) > ws_size) kg = 6;
                        }
                    }
                }
            }
        }
    }
    unsigned short* partial = (unsigned short*)(ws + fixed + (size_t)g * 25165824);

    k_prep_all<<<dim3(5632), dim3(256), 0, stream>>>(x, phi, Mp, Mm, xb, ToepA, MbT);

    for (int b0 = 0; b0 < 4; b0 += g) {
        k_stage1<<<dim3(8, 96, g), dim3(256), 0, stream>>>(xb + (size_t)b0 * 262144, MbT, Zbuf);
        k_stage2<<<dim3(4, 2 * g, kg), dim3(256), 0, stream>>>(Zbuf, ToepA, partial, 48 / kg);
        k_reduce<<<dim3(128, g), dim3(256), 0, stream>>>(partial, out + (size_t)b0 * 262144, kg);
    }
}

// Round 17
// 132.850 us; speedup vs baseline: 1.1343x; 1.0095x over previous
//
#include <hip/hip_runtime.h>

// MiniSTU: out[b,l,o] = sum_k sum_{s<=l} phi[l-s,k]*(x@Mp[k])[o] + (-1)^(l-s)-weighted Mm term
// Stage 1: Z[b][kk][o][s] gl16 counted-vmcnt GEMM, 128s x 256o tile (4 waves of 64x128),
//          32-K chunks, A 2x8KB + B 3x16KB = 64KB LDS (2 blocks/CU).
// Stage 2: 128l x 128o Toeplitz GEMM (r12 structure), A 2x16KB + Z 3x16KB (80KB),
//          counted vmcnt(4), XCD-chunked remap. bf16 partial.
// Swizzle pairs: xb/MbT are 32-scope (stage1-internal); Z/ToepA are 64-scope (stage2 pair).

#define ZB_ 12582912  // Z elems per batch (48*256*1024)

typedef __attribute__((ext_vector_type(8))) short bf16x8;
typedef __attribute__((ext_vector_type(4))) float f32x4;

__device__ inline unsigned short f2bf(float f) {
    unsigned u = __float_as_uint(f);
    u += 0x7FFFu + ((u >> 16) & 1u);   // RNE
    return (unsigned short)(u >> 16);
}

__device__ inline float bf2f(unsigned short s) {
    unsigned u = ((unsigned)s) << 16;
    return __uint_as_float(u);
}

__device__ inline void gl16(const unsigned short* g, unsigned short* l) {
    __builtin_amdgcn_global_load_lds((const __attribute__((address_space(1))) void*)g,
                                     (__attribute__((address_space(3))) void*)l, 16, 0, 0);
}

// ---- merged prep: [0,1024) prep_x | [1024,1792) prep_toep | [1792,4864) transpose_M
__global__ __launch_bounds__(256) void k_prep_all(const float* __restrict__ x,
                                                  const float* __restrict__ phi,
                                                  const float* __restrict__ Mp,
                                                  const float* __restrict__ Mm,
                                                  unsigned short* __restrict__ xb,
                                                  unsigned short* __restrict__ ToepA,
                                                  unsigned short* __restrict__ MbT) {
    __shared__ float tile[32][33];
    int bid = blockIdx.x, tid = threadIdx.x;
    if (bid < 1024) {
        // x (f32) -> xb (bf16), i pre-swizzled within 32-chunks by ((s>>1)&3)<<3
        int i = (bid * 256 + tid) * 4;
        float4 v = *(const float4*)(x + i);
        ushort4 o;
        o.x = f2bf(v.x); o.y = f2bf(v.y); o.z = f2bf(v.z); o.w = f2bf(v.w);
        int row = i >> 8, col = i & 255;
        int dst = (row << 8) | (col & 224) | ((col & 31) ^ (((row >> 1) & 3) << 3));
        *(ushort4*)(xb + dst) = o;
    } else if (bid < 1792) {
        // ToepA[kk][didx][i][j'] = sgn*phi[(didx-1)*64+i-j][k], j' = j ^ ((i&7)<<3)  (64-scope)
        int r = bid - 1024;
        int kk = r >> 4;
        int dm = (r & 15) - 1;
        int k = (kk < 24) ? kk : kk - 24;
        int i = tid >> 1, j0 = (tid & 1) * 32;
        unsigned short* dst = ToepA + ((size_t)kk * 16 + (dm + 1)) * 8192 + i * 64;
        int sw = (i & 7) << 3;
#pragma unroll
        for (int q = 0; q < 8; ++q) {
            int j = j0 + q * 4;
            unsigned short e[4];
#pragma unroll
            for (int ee = 0; ee < 4; ++ee) {
                int t = dm * 64 + i - (j + ee);
                float v = 0.f;
                if (t >= 0 && t < 1024) {
                    v = phi[t * 24 + k];
                    if (kk >= 24 && (t & 1)) v = -v;
                }
                e[ee] = f2bf(v);
            }
            ushort4 ov; ov.x = e[0]; ov.y = e[1]; ov.z = e[2]; ov.w = e[3];
            *(ushort4*)(dst + (j ^ sw)) = ov;
        }
    } else {
        // MbT[kk][o][i'] = M(kk)[i][o], i pre-swizzled within 32 by ((o>>1)&3)<<3
        int flat = bid - 1792;
        int kk = flat >> 6, rr = flat & 63;
        int i0 = (rr >> 3) * 32, o0 = (rr & 7) * 32;
        int tx = tid & 31, ty = tid >> 5;
        const float* src = ((kk < 24) ? Mp : Mm) + (size_t)((kk < 24) ? kk : kk - 24) * 65536;
        for (int j = 0; j < 4; ++j)
            tile[ty + j * 8][tx] = src[(i0 + ty + j * 8) * 256 + o0 + tx];
        __syncthreads();
        for (int j = 0; j < 4; ++j) {
            int orow = o0 + ty + j * 8, i = i0 + tx;
            int ic = (i & 224) | ((i & 31) ^ (((orow >> 1) & 3) << 3));
            MbT[(size_t)kk * 65536 + orow * 256 + ic] = f2bf(tile[tx][ty + j * 8]);
        }
    }
}

// ---- stage 1: work (8 m-tiles, 48 kk, g batches), 256 thr (4 waves) ----------
// Tile 128s x 256o, wave (wm,wn) owns 64s x 128o (acc 4x8). 32-K chunks x8.
// A(xb) 2x8KB 1-ahead + B(MbT) 3x16KB 2-ahead = 64KB LDS. vmcnt(4) steady.
__global__ __launch_bounds__(256, 2) void k_stage1(const unsigned short* __restrict__ xb0,
                                                   const unsigned short* __restrict__ MbT,
                                                   unsigned short* __restrict__ Z) {
    __shared__ unsigned short Ab[2][4096];
    __shared__ unsigned short Bb[3][8192];
    int tid = threadIdx.x, lane = tid & 63, w = tid >> 6;
    int wm = w >> 1, wn = w & 1;

    // XCD-chunked bijective remap: 8 m-blocks sharing a B-panel co-locate.
    int nwg = 384 * gridDim.z;
    int orig = blockIdx.x + blockIdx.y * 8 + blockIdx.z * 384;
    int wg = (orig & 7) * (nwg >> 3) + (orig >> 3);
    int m0 = (wg & 7) * 128;
    int rem = wg >> 3;
    int kk = rem % 48;
    int b  = rem / 48;

    const unsigned short* xb_b = xb0 + (size_t)b * 262144;
    unsigned short* Zb = Z + (size_t)b * ZB_;
    const unsigned short* Bsrc = MbT + (size_t)kk * 65536;
    int l16 = lane & 15, kofs = (lane >> 4) * 8;
    int sw32 = ((l16 >> 1) & 3) << 3;
    int r4l = lane >> 2, c4 = (lane & 3) * 8;

    // A staging: 2 slices of [64s][32k]; B staging: 4 slices of [64o][32k]
    int arow[2], aofs[2], brow[4], bofs[4];
#pragma unroll
    for (int q = 0; q < 2; ++q) {
        int rr = q * 64 + w * 16 + r4l;
        arow[q] = (m0 + rr) * 256 + c4;
        aofs[q] = q * 2048 + w * 512;
    }
#pragma unroll
    for (int q = 0; q < 4; ++q) {
        int rr = q * 64 + w * 16 + r4l;
        brow[q] = rr * 256 + c4;
        bofs[q] = q * 2048 + w * 512;
    }

    f32x4 acc[4][8];
    for (int i = 0; i < 4; ++i)
        for (int j = 0; j < 8; ++j) {
            acc[i][j][0] = 0.f; acc[i][j][1] = 0.f; acc[i][j][2] = 0.f; acc[i][j][3] = 0.f;
        }

    auto stageA = [&](int bi, int ko) {
#pragma unroll
        for (int q = 0; q < 2; ++q) gl16(xb_b + arow[q] + ko * 32, &Ab[bi][0] + aofs[q]);
    };
    auto stageB = [&](int bi, int ko) {
#pragma unroll
        for (int q = 0; q < 4; ++q) gl16(Bsrc + brow[q] + ko * 32, &Bb[bi][0] + bofs[q]);
    };

    stageA(0, 0); stageB(0, 0); stageB(1, 1);   // 10 loads in flight

    for (int ko = 0; ko < 8; ++ko) {
        if (ko < 7) { asm volatile("s_waitcnt vmcnt(4)" ::: "memory"); }
        else        { asm volatile("s_waitcnt vmcnt(0)" ::: "memory"); }
        __builtin_amdgcn_sched_barrier(0);
        __builtin_amdgcn_s_barrier();
        __builtin_amdgcn_sched_barrier(0);
        if (ko < 7) stageA((ko + 1) & 1, ko + 1);
        if (ko < 6) stageB((ko + 2) % 3, ko + 2);

        const unsigned short* Abase = &Ab[ko & 1][0];
        const unsigned short* Bbase = &Bb[ko % 3][0];
        int koX = kofs ^ sw32;
        bf16x8 af[4], bfv[8];
#pragma unroll
        for (int mi = 0; mi < 4; ++mi)
            af[mi] = *(const bf16x8*)(Abase + (wm * 64 + mi * 16 + l16) * 32 + koX);
#pragma unroll
        for (int ni = 0; ni < 8; ++ni)
            bfv[ni] = *(const bf16x8*)(Bbase + (wn * 128 + ni * 16 + l16) * 32 + koX);
        __builtin_amdgcn_s_setprio(1);
#pragma unroll
        for (int mi = 0; mi < 4; ++mi)
#pragma unroll
            for (int ni = 0; ni < 8; ++ni)
                acc[mi][ni] = __builtin_amdgcn_mfma_f32_16x16x32_bf16(af[mi], bfv[ni], acc[mi][ni], 0, 0, 0);
        __builtin_amdgcn_s_setprio(0);
    }

    // store Z with s pre-swizzled by (o&7)<<3 within 64-chunks (stage2's 64-scope pair)
    int r4 = (lane >> 4) * 4;
    for (int mi = 0; mi < 4; ++mi) {
        int sbase = m0 + wm * 64 + mi * 16 + r4;
        for (int ni = 0; ni < 8; ++ni) {
            int o = wn * 128 + ni * 16 + l16;
            int sidx = sbase ^ ((o & 7) << 3);
            ushort4 pk;
            pk.x = f2bf(acc[mi][ni][0]); pk.y = f2bf(acc[mi][ni][1]);
            pk.z = f2bf(acc[mi][ni][2]); pk.w = f2bf(acc[mi][ni][3]);
            *(ushort4*)(Zb + (size_t)kk * 262144 + (size_t)o * 1024 + sidx) = pk;
        }
    }
}

// ---- stage 2: grid (4 diag-pairs, 2 o-tiles x g batches, kg), 256 thr --------
// r12 structure: 64-wide s-chunks, A 2x16KB 1-ahead + Z 3x16KB 2-ahead (80KB).
__global__ __launch_bounds__(256, 2) void k_stage2(const unsigned short* __restrict__ Z,
                                                   const unsigned short* __restrict__ ToepA,
                                                   unsigned short* __restrict__ partial, int kkpg) {
    __shared__ unsigned short Abuf[2][8192];
    __shared__ unsigned short Zbuf[3][8192];
    int tid = threadIdx.x, lane = tid & 63, w = tid >> 6;
    int wm = w >> 1, wn = w & 1;

    // XCD-chunked bijective remap (nwg % 8 == 0 always here)
    int gy = gridDim.y, nwg = 4 * gy * gridDim.z;
    int orig = blockIdx.x + blockIdx.y * 4 + blockIdx.z * 4 * gy;
    int wg = (orig & 7) * (nwg >> 3) + (orig >> 3);
    int pr = wg & 3;
    int yy = (wg >> 2) % gy;
    int zz = (wg >> 2) / gy;
    int o0 = (yy & 1) * 128;
    int b  = yy >> 1;
    int kgi = zz;
    int kk0 = kgi * kkpg;

    int l16 = lane & 15, kofs = (lane >> 4) * 8;
    int sw = (l16 & 7) << 3;
    int r8 = lane >> 3, cg = lane & 7;

    const unsigned short* Zb = Z + (size_t)b * ZB_;
    unsigned short* pb = partial + ((size_t)b * gridDim.z + kgi) * 262144;

    int arow[4], zrow[4], lofs[4];
#pragma unroll
    for (int q = 0; q < 4; ++q) {
        int rr = q * 32 + w * 8 + r8;
        arow[q] = rr * 64 + cg * 8;
        zrow[q] = (o0 + rr) * 1024 + cg * 8;
        lofs[q] = q * 2048 + w * 512;
    }

    for (int half = 0; half < 2; ++half) {
        int lb = half ? (7 - pr) : pr;
        int l0 = lb * 128;
        int nch = 2 * lb + 2;
        int total = kkpg * nch;

        f32x4 acc[4][4];
        for (int i = 0; i < 4; ++i)
            for (int j = 0; j < 4; ++j) {
                acc[i][j][0] = 0.f; acc[i][j][1] = 0.f; acc[i][j][2] = 0.f; acc[i][j][3] = 0.f;
            }

        __syncthreads();   // previous-half readers done before restaging LDS

        auto stageA = [&](int bi, int kka, int didx) {
            const unsigned short* gA = ToepA + ((size_t)kka * 16 + didx) * 8192;
#pragma unroll
            for (int q = 0; q < 4; ++q) gl16(gA + arow[q], &Abuf[bi][0] + lofs[q]);
        };
        auto stageZ = [&](int bi, int kka, int s0) {
            const unsigned short* gZ = Zb + (size_t)kka * 262144 + s0;
#pragma unroll
            for (int q = 0; q < 4; ++q) gl16(gZ + zrow[q], &Zbuf[bi][0] + lofs[q]);
        };
        auto compute = [&](int ba, int bz) {
            const unsigned short* Abase = &Abuf[ba][0];
            const unsigned short* Zbase = &Zbuf[bz][0];
            __builtin_amdgcn_s_setprio(1);
#pragma unroll
            for (int ks = 0; ks < 2; ++ks) {
                int koX = (ks * 32 + kofs) ^ sw;
                bf16x8 af[4], bfv[4];
#pragma unroll
                for (int mi = 0; mi < 4; ++mi)
                    af[mi] = *(const bf16x8*)(Abase + (wm * 64 + mi * 16 + l16) * 64 + koX);
#pragma unroll
                for (int ni = 0; ni < 4; ++ni)
                    bfv[ni] = *(const bf16x8*)(Zbase + (wn * 64 + ni * 16 + l16) * 64 + koX);
#pragma unroll
                for (int mi = 0; mi < 4; ++mi)
#pragma unroll
                    for (int ni = 0; ni < 4; ++ni)
                        acc[mi][ni] = __builtin_amdgcn_mfma_f32_16x16x32_bf16(af[mi], bfv[ni], acc[mi][ni], 0, 0, 0);
            }
            __builtin_amdgcn_s_setprio(0);
        };

        // prologue: A(0), Z(0), Z(1)
        stageA(0, kk0, 2 * lb + 1);
        stageZ(0, kk0, 0);
        stageZ(1, kk0, 64);

        int scA = 1, kkA = 0;
        int scZ = 2, kkZ = 0;
        if (scZ == nch) { scZ = 0; kkZ = 1; }
        int jz = 2;

        for (int j = 0; j < total - 1; ++j) {
            asm volatile("s_waitcnt vmcnt(4)" ::: "memory");
            __builtin_amdgcn_sched_barrier(0);
            __builtin_amdgcn_s_barrier();
            __builtin_amdgcn_sched_barrier(0);
            stageA((j + 1) & 1, kk0 + kkA, 2 * lb - scA + 1);
            ++scA; if (scA == nch) { scA = 0; ++kkA; }
            if (jz < total) {
                stageZ(jz % 3, kk0 + kkZ, scZ * 64);
                ++scZ; if (scZ == nch) { scZ = 0; ++kkZ; }
                ++jz;
            }
            compute(j & 1, j % 3);
        }
        asm volatile("s_waitcnt vmcnt(0)" ::: "memory");
        __builtin_amdgcn_sched_barrier(0);
        __builtin_amdgcn_s_barrier();
        __builtin_amdgcn_sched_barrier(0);
        compute((total - 1) & 1, (total - 1) % 3);

        int r4 = (lane >> 4) * 4;
        for (int mi = 0; mi < 4; ++mi) {
            int l = l0 + wm * 64 + mi * 16 + r4;
            for (int ni = 0; ni < 4; ++ni) {
                int o = o0 + wn * 64 + ni * 16 + l16;
                unsigned short* dst = pb + (size_t)l * 256 + o;
                dst[0]   = f2bf(acc[mi][ni][0]);
                dst[256] = f2bf(acc[mi][ni][1]);
                dst[512] = f2bf(acc[mi][ni][2]);
                dst[768] = f2bf(acc[mi][ni][3]);
            }
        }
    }
}

// ---- reduce: out[b][l][o] = sum_kg partial[b][kg][l][o] (bf16 -> f32) --------
__global__ void k_reduce(const unsigned short* __restrict__ partial, float* __restrict__ outg, int kg) {
    const unsigned short* pb = partial + (size_t)blockIdx.y * kg * 262144;
    int i = (blockIdx.x * 256 + threadIdx.x) * 8;
    float s[8];
#pragma unroll
    for (int j = 0; j < 8; ++j) s[j] = 0.f;
    for (int kgi = 0; kgi < kg; ++kgi) {
        uint4 v = *(const uint4*)(pb + (size_t)kgi * 262144 + i);
        unsigned vv[4] = {v.x, v.y, v.z, v.w};
#pragma unroll
        for (int q = 0; q < 4; ++q) {
            s[q * 2]     += bf2f((unsigned short)(vv[q] & 0xFFFF));
            s[q * 2 + 1] += bf2f((unsigned short)(vv[q] >> 16));
        }
    }
    float4 o0, o1;
    o0.x = s[0]; o0.y = s[1]; o0.z = s[2]; o0.w = s[3];
    o1.x = s[4]; o1.y = s[5]; o1.z = s[6]; o1.w = s[7];
    float* dst = outg + (size_t)blockIdx.y * 262144 + i;
    *(float4*)(dst) = o0;
    *(float4*)(dst + 4) = o1;
}

extern "C" void kernel_launch(void* const* d_in, const int* in_sizes, int n_in,
                              void* d_out, int out_size, void* d_ws, size_t ws_size,
                              hipStream_t stream) {
    const float* x   = (const float*)d_in[0];   // [4,1024,256]
    const float* phi = (const float*)d_in[1];   // [1024,24]
    const float* Mp  = (const float*)d_in[2];   // [24,256,256]
    const float* Mm  = (const float*)d_in[3];   // [24,256,256]
    float* out = (float*)d_out;                 // [4,1024,256]

    char* ws = (char*)d_ws;
    unsigned short* xb    = (unsigned short*)(ws);             //  2,097,152 B
    unsigned short* MbT   = (unsigned short*)(ws + 2097152);   //  6,291,456 B
    unsigned short* ToepA = (unsigned short*)(ws + 8388608);   // 12,582,912 B
    unsigned short* Zbuf  = (unsigned short*)(ws + 20971520);  // g * 25,165,824 B
    const size_t fixed = 20971520;

    int g = 4, kg = 16;
    auto need = [&](int gg, int kk) {
        return fixed + (size_t)gg * 25165824 + (size_t)gg * (size_t)kk * 524288;
    };
    if (need(4, 16) > ws_size) {
        kg = 12;
        if (need(4, 12) > ws_size) {
            g = 2; kg = 16;
            if (need(2, 16) > ws_size) {
                kg = 12;
                if (need(2, 12) > ws_size) {
                    g = 1; kg = 16;
                    if (need(1, 16) > ws_size) {
                        kg = 12;
                        if (need(1, 12) > ws_size) kg = 6;
                    }
                }
            }
        }
    }
    unsigned short* partial = (unsigned short*)(ws + fixed + (size_t)g * 25165824);

    k_prep_all<<<dim3(4864), dim3(256), 0, stream>>>(x, phi, Mp, Mm, xb, ToepA, MbT);

    for (int b0 = 0; b0 < 4; b0 += g) {
        k_stage1<<<dim3(8, 48, g), dim3(256), 0, stream>>>(xb + (size_t)b0 * 262144, MbT, Zbuf);
        k_stage2<<<dim3(4, 2 * g, kg), dim3(256), 0, stream>>>(Zbuf, ToepA, partial, 48 / kg);
        k_reduce<<<dim3(128, g), dim3(256), 0, stream>>>(partial, out + (size_t)b0 * 262144, kg);
    }
}

// Round 18
// 130.729 us; speedup vs baseline: 1.1527x; 1.0162x over previous
//
#include <hip/hip_runtime.h>

// MiniSTU: out[b,l,o] = sum_k sum_{s<=l} phi[l-s,k]*(x@Mp[k])[o] + (-1)^(l-s)-weighted Mm term
// Stage 1: Z[b][kk][o][s] gl16 counted-vmcnt GEMM, 32-K chunks, 40KB LDS (4 blocks/CU),
//          XCD-chunked remap. xb/MbT pre-swizzled within 32-col chunks.
// Stage 2: 128l x 128o Toeplitz GEMM, gl16 counted-vmcnt (A 1-ahead LDS, Z 2-ahead LDS),
//          XCD-chunked remap, 64-col swizzle pair (ToepA/Z). bf16 partial.
// Best measured config: 129.9 us (r10), reproduced 130.8 (r12).

#define ZB_ 12582912  // Z elems per batch (48*256*1024)

typedef __attribute__((ext_vector_type(8))) short bf16x8;
typedef __attribute__((ext_vector_type(4))) float f32x4;

__device__ inline unsigned short f2bf(float f) {
    unsigned u = __float_as_uint(f);
    u += 0x7FFFu + ((u >> 16) & 1u);   // RNE
    return (unsigned short)(u >> 16);
}

__device__ inline float bf2f(unsigned short s) {
    unsigned u = ((unsigned)s) << 16;
    return __uint_as_float(u);
}

__device__ inline void gl16(const unsigned short* g, unsigned short* l) {
    __builtin_amdgcn_global_load_lds((const __attribute__((address_space(1))) void*)g,
                                     (__attribute__((address_space(3))) void*)l, 16, 0, 0);
}

// ---- merged prep: [0,1024) prep_x | [1024,1792) prep_toep | [1792,4864) transpose_M
__global__ __launch_bounds__(256) void k_prep_all(const float* __restrict__ x,
                                                  const float* __restrict__ phi,
                                                  const float* __restrict__ Mp,
                                                  const float* __restrict__ Mm,
                                                  unsigned short* __restrict__ xb,
                                                  unsigned short* __restrict__ ToepA,
                                                  unsigned short* __restrict__ MbT) {
    __shared__ float tile[32][33];
    int bid = blockIdx.x, tid = threadIdx.x;
    if (bid < 1024) {
        // x (f32) -> xb (bf16), i pre-swizzled within 32-chunks by ((s>>1)&3)<<3
        int i = (bid * 256 + tid) * 4;
        float4 v = *(const float4*)(x + i);
        ushort4 o;
        o.x = f2bf(v.x); o.y = f2bf(v.y); o.z = f2bf(v.z); o.w = f2bf(v.w);
        int row = i >> 8, col = i & 255;
        int dst = (row << 8) | (col & 224) | ((col & 31) ^ (((row >> 1) & 3) << 3));
        *(ushort4*)(xb + dst) = o;
    } else if (bid < 1792) {
        // ToepA[kk][didx][i][j'] = sgn*phi[(didx-1)*64+i-j][k], j' = j ^ ((i&7)<<3)
        int r = bid - 1024;
        int kk = r >> 4;
        int dm = (r & 15) - 1;
        int k = (kk < 24) ? kk : kk - 24;
        int i = tid >> 1, j0 = (tid & 1) * 32;
        unsigned short* dst = ToepA + ((size_t)kk * 16 + (dm + 1)) * 8192 + i * 64;
        int sw = (i & 7) << 3;
#pragma unroll
        for (int q = 0; q < 8; ++q) {
            int j = j0 + q * 4;
            unsigned short e[4];
#pragma unroll
            for (int ee = 0; ee < 4; ++ee) {
                int t = dm * 64 + i - (j + ee);
                float v = 0.f;
                if (t >= 0 && t < 1024) {
                    v = phi[t * 24 + k];
                    if (kk >= 24 && (t & 1)) v = -v;
                }
                e[ee] = f2bf(v);
            }
            ushort4 ov; ov.x = e[0]; ov.y = e[1]; ov.z = e[2]; ov.w = e[3];
            *(ushort4*)(dst + (j ^ sw)) = ov;
        }
    } else {
        // MbT[kk][o][i'] = M(kk)[i][o], i pre-swizzled within 32 by ((o>>1)&3)<<3
        int flat = bid - 1792;
        int kk = flat >> 6, rr = flat & 63;
        int i0 = (rr >> 3) * 32, o0 = (rr & 7) * 32;
        int tx = tid & 31, ty = tid >> 5;
        const float* src = ((kk < 24) ? Mp : Mm) + (size_t)((kk < 24) ? kk : kk - 24) * 65536;
        for (int j = 0; j < 4; ++j)
            tile[ty + j * 8][tx] = src[(i0 + ty + j * 8) * 256 + o0 + tx];
        __syncthreads();
        for (int j = 0; j < 4; ++j) {
            int orow = o0 + ty + j * 8, i = i0 + tx;
            int ic = (i & 224) | ((i & 31) ^ (((orow >> 1) & 3) << 3));
            MbT[(size_t)kk * 65536 + orow * 256 + ic] = f2bf(tile[tx][ty + j * 8]);
        }
    }
}

// ---- stage 1: work (8 m-tiles, 96 = 48kk x 2 o-halves, g batches), 256 thr ---
// 32-K chunks x8, Ab 2-buf 1-ahead + Bb 3-buf 2-ahead (40KB), 4 blocks/CU.
__global__ __launch_bounds__(256, 4) void k_stage1(const unsigned short* __restrict__ xb0,
                                                   const unsigned short* __restrict__ MbT,
                                                   unsigned short* __restrict__ Z) {
    __shared__ unsigned short Ab[2][4096];
    __shared__ unsigned short Bb[3][4096];
    int tid = threadIdx.x, lane = tid & 63, w = tid >> 6;
    int wm = w >> 1, wn = w & 1;

    // XCD-chunked bijective remap: consecutive work ids co-locate on an XCD.
    int nwg = 768 * gridDim.z;
    int orig = blockIdx.x + blockIdx.y * 8 + blockIdx.z * 768;
    int wg = (orig & 7) * (nwg >> 3) + (orig >> 3);
    int m0 = (wg & 7) * 128;
    int rem = wg >> 3;
    int yy = rem % 96;
    int b  = rem / 96;
    int kk = yy >> 1;
    int o0 = (yy & 1) * 128;

    const unsigned short* xb_b = xb0 + (size_t)b * 262144;
    unsigned short* Zb = Z + (size_t)b * ZB_;
    const unsigned short* Bsrc = MbT + (size_t)kk * 65536;
    int l16 = lane & 15, kofs = (lane >> 4) * 8;
    int sw32 = ((l16 >> 1) & 3) << 3;
    int r4l = lane >> 2, c4 = (lane & 3) * 8;

    int arow[2], brow[2], lofs[2];
#pragma unroll
    for (int q = 0; q < 2; ++q) {
        int rr = q * 64 + w * 16 + r4l;
        arow[q] = (m0 + rr) * 256 + c4;
        brow[q] = (o0 + rr) * 256 + c4;
        lofs[q] = q * 2048 + w * 512;
    }

    f32x4 acc[4][4];
    for (int i = 0; i < 4; ++i)
        for (int j = 0; j < 4; ++j) {
            acc[i][j][0] = 0.f; acc[i][j][1] = 0.f; acc[i][j][2] = 0.f; acc[i][j][3] = 0.f;
        }

    auto stageA = [&](int bi, int ko) {
#pragma unroll
        for (int q = 0; q < 2; ++q) gl16(xb_b + arow[q] + ko * 32, &Ab[bi][0] + lofs[q]);
    };
    auto stageB = [&](int bi, int ko) {
#pragma unroll
        for (int q = 0; q < 2; ++q) gl16(Bsrc + brow[q] + ko * 32, &Bb[bi][0] + lofs[q]);
    };

    stageA(0, 0); stageB(0, 0); stageB(1, 1);   // 6 loads in flight

    for (int ko = 0; ko < 8; ++ko) {
        if (ko < 7) { asm volatile("s_waitcnt vmcnt(2)" ::: "memory"); }
        else        { asm volatile("s_waitcnt vmcnt(0)" ::: "memory"); }
        __builtin_amdgcn_sched_barrier(0);
        __builtin_amdgcn_s_barrier();
        __builtin_amdgcn_sched_barrier(0);
        if (ko < 7) stageA((ko + 1) & 1, ko + 1);
        if (ko < 6) stageB((ko + 2) % 3, ko + 2);

        const unsigned short* Abase = &Ab[ko & 1][0];
        const unsigned short* Bbase = &Bb[ko % 3][0];
        int koX = kofs ^ sw32;
        bf16x8 af[4], bfv[4];
#pragma unroll
        for (int mi = 0; mi < 4; ++mi)
            af[mi] = *(const bf16x8*)(Abase + (wm * 64 + mi * 16 + l16) * 32 + koX);
#pragma unroll
        for (int ni = 0; ni < 4; ++ni)
            bfv[ni] = *(const bf16x8*)(Bbase + (wn * 64 + ni * 16 + l16) * 32 + koX);
        __builtin_amdgcn_s_setprio(1);
#pragma unroll
        for (int mi = 0; mi < 4; ++mi)
#pragma unroll
            for (int ni = 0; ni < 4; ++ni)
                acc[mi][ni] = __builtin_amdgcn_mfma_f32_16x16x32_bf16(af[mi], bfv[ni], acc[mi][ni], 0, 0, 0);
        __builtin_amdgcn_s_setprio(0);
    }

    // store Z with s pre-swizzled by (o&7)<<3 within 64-chunks (stage2's pair)
    int r4 = (lane >> 4) * 4;
    for (int mi = 0; mi < 4; ++mi) {
        int sbase = m0 + wm * 64 + mi * 16 + r4;
        for (int ni = 0; ni < 4; ++ni) {
            int o = o0 + wn * 64 + ni * 16 + l16;
            ushort4 pk;
            pk.x = f2bf(acc[mi][ni][0]); pk.y = f2bf(acc[mi][ni][1]);
            pk.z = f2bf(acc[mi][ni][2]); pk.w = f2bf(acc[mi][ni][3]);
            *(ushort4*)(Zb + (size_t)kk * 262144 + (size_t)o * 1024 + (sbase ^ ((o & 7) << 3))) = pk;
        }
    }
}

// ---- stage 2: grid (4 diag-pairs, 2 o-tiles x g batches, kg), 256 thr --------
// Counted-vmcnt pipeline: A 1-ahead (2 bufs), Z 2-ahead (3 bufs). LDS 80 KB.
__global__ __launch_bounds__(256, 2) void k_stage2(const unsigned short* __restrict__ Z,
                                                   const unsigned short* __restrict__ ToepA,
                                                   unsigned short* __restrict__ partial, int kkpg) {
    __shared__ unsigned short Abuf[2][8192];
    __shared__ unsigned short Zbuf[3][8192];
    int tid = threadIdx.x, lane = tid & 63, w = tid >> 6;
    int wm = w >> 1, wn = w & 1;

    // XCD-chunked bijective remap (nwg % 8 == 0 always here)
    int gy = gridDim.y, nwg = 4 * gy * gridDim.z;
    int orig = blockIdx.x + blockIdx.y * 4 + blockIdx.z * 4 * gy;
    int wg = (orig & 7) * (nwg >> 3) + (orig >> 3);
    int pr = wg & 3;
    int yy = (wg >> 2) % gy;
    int zz = (wg >> 2) / gy;
    int o0 = (yy & 1) * 128;
    int b  = yy >> 1;
    int kgi = zz;
    int kk0 = kgi * kkpg;

    int l16 = lane & 15, kofs = (lane >> 4) * 8;
    int sw = (l16 & 7) << 3;
    int r8 = lane >> 3, cg = lane & 7;

    const unsigned short* Zb = Z + (size_t)b * ZB_;
    unsigned short* pb = partial + ((size_t)b * gridDim.z + kgi) * 262144;

    int arow[4], zrow[4], lofs[4];
#pragma unroll
    for (int q = 0; q < 4; ++q) {
        int rr = q * 32 + w * 8 + r8;
        arow[q] = rr * 64 + cg * 8;
        zrow[q] = (o0 + rr) * 1024 + cg * 8;
        lofs[q] = q * 2048 + w * 512;
    }

    for (int half = 0; half < 2; ++half) {
        int lb = half ? (7 - pr) : pr;
        int l0 = lb * 128;
        int nch = 2 * lb + 2;
        int total = kkpg * nch;

        f32x4 acc[4][4];
        for (int i = 0; i < 4; ++i)
            for (int j = 0; j < 4; ++j) {
                acc[i][j][0] = 0.f; acc[i][j][1] = 0.f; acc[i][j][2] = 0.f; acc[i][j][3] = 0.f;
            }

        __syncthreads();   // previous-half readers done before restaging LDS

        auto stageA = [&](int bi, int kka, int didx) {
            const unsigned short* gA = ToepA + ((size_t)kka * 16 + didx) * 8192;
#pragma unroll
            for (int q = 0; q < 4; ++q) gl16(gA + arow[q], &Abuf[bi][0] + lofs[q]);
        };
        auto stageZ = [&](int bi, int kka, int s0) {
            const unsigned short* gZ = Zb + (size_t)kka * 262144 + s0;
#pragma unroll
            for (int q = 0; q < 4; ++q) gl16(gZ + zrow[q], &Zbuf[bi][0] + lofs[q]);
        };
        auto compute = [&](int ba, int bz) {
            const unsigned short* Abase = &Abuf[ba][0];
            const unsigned short* Zbase = &Zbuf[bz][0];
            __builtin_amdgcn_s_setprio(1);
#pragma unroll
            for (int ks = 0; ks < 2; ++ks) {
                int koX = (ks * 32 + kofs) ^ sw;
                bf16x8 af[4], bfv[4];
#pragma unroll
                for (int mi = 0; mi < 4; ++mi)
                    af[mi] = *(const bf16x8*)(Abase + (wm * 64 + mi * 16 + l16) * 64 + koX);
#pragma unroll
                for (int ni = 0; ni < 4; ++ni)
                    bfv[ni] = *(const bf16x8*)(Zbase + (wn * 64 + ni * 16 + l16) * 64 + koX);
#pragma unroll
                for (int mi = 0; mi < 4; ++mi)
#pragma unroll
                    for (int ni = 0; ni < 4; ++ni)
                        acc[mi][ni] = __builtin_amdgcn_mfma_f32_16x16x32_bf16(af[mi], bfv[ni], acc[mi][ni], 0, 0, 0);
            }
            __builtin_amdgcn_s_setprio(0);
        };

        // prologue: A(0), Z(0), Z(1)
        stageA(0, kk0, 2 * lb + 1);
        stageZ(0, kk0, 0);
        stageZ(1, kk0, 64);

        int scA = 1, kkA = 0;
        int scZ = 2, kkZ = 0;
        if (scZ == nch) { scZ = 0; kkZ = 1; }
        int jz = 2;

        for (int j = 0; j < total - 1; ++j) {
            asm volatile("s_waitcnt vmcnt(4)" ::: "memory");
            __builtin_amdgcn_sched_barrier(0);
            __builtin_amdgcn_s_barrier();
            __builtin_amdgcn_sched_barrier(0);
            stageA((j + 1) & 1, kk0 + kkA, 2 * lb - scA + 1);
            ++scA; if (scA == nch) { scA = 0; ++kkA; }
            if (jz < total) {
                stageZ(jz % 3, kk0 + kkZ, scZ * 64);
                ++scZ; if (scZ == nch) { scZ = 0; ++kkZ; }
                ++jz;
            }
            compute(j & 1, j % 3);
        }
        asm volatile("s_waitcnt vmcnt(0)" ::: "memory");
        __builtin_amdgcn_sched_barrier(0);
        __builtin_amdgcn_s_barrier();
        __builtin_amdgcn_sched_barrier(0);
        compute((total - 1) & 1, (total - 1) % 3);

        int r4 = (lane >> 4) * 4;
        for (int mi = 0; mi < 4; ++mi) {
            int l = l0 + wm * 64 + mi * 16 + r4;
            for (int ni = 0; ni < 4; ++ni) {
                int o = o0 + wn * 64 + ni * 16 + l16;
                unsigned short* dst = pb + (size_t)l * 256 + o;
                dst[0]   = f2bf(acc[mi][ni][0]);
                dst[256] = f2bf(acc[mi][ni][1]);
                dst[512] = f2bf(acc[mi][ni][2]);
                dst[768] = f2bf(acc[mi][ni][3]);
            }
        }
    }
}

// ---- reduce: out[b][l][o] = sum_kg partial[b][kg][l][o] (bf16 -> f32) --------
__global__ void k_reduce(const unsigned short* __restrict__ partial, float* __restrict__ outg, int kg) {
    const unsigned short* pb = partial + (size_t)blockIdx.y * kg * 262144;
    int i = (blockIdx.x * 256 + threadIdx.x) * 8;
    float s[8];
#pragma unroll
    for (int j = 0; j < 8; ++j) s[j] = 0.f;
    for (int kgi = 0; kgi < kg; ++kgi) {
        uint4 v = *(const uint4*)(pb + (size_t)kgi * 262144 + i);
        unsigned vv[4] = {v.x, v.y, v.z, v.w};
#pragma unroll
        for (int q = 0; q < 4; ++q) {
            s[q * 2]     += bf2f((unsigned short)(vv[q] & 0xFFFF));
            s[q * 2 + 1] += bf2f((unsigned short)(vv[q] >> 16));
        }
    }
    float4 o0, o1;
    o0.x = s[0]; o0.y = s[1]; o0.z = s[2]; o0.w = s[3];
    o1.x = s[4]; o1.y = s[5]; o1.z = s[6]; o1.w = s[7];
    float* dst = outg + (size_t)blockIdx.y * 262144 + i;
    *(float4*)(dst) = o0;
    *(float4*)(dst + 4) = o1;
}

extern "C" void kernel_launch(void* const* d_in, const int* in_sizes, int n_in,
                              void* d_out, int out_size, void* d_ws, size_t ws_size,
                              hipStream_t stream) {
    const float* x   = (const float*)d_in[0];   // [4,1024,256]
    const float* phi = (const float*)d_in[1];   // [1024,24]
    const float* Mp  = (const float*)d_in[2];   // [24,256,256]
    const float* Mm  = (const float*)d_in[3];   // [24,256,256]
    float* out = (float*)d_out;                 // [4,1024,256]

    char* ws = (char*)d_ws;
    unsigned short* xb    = (unsigned short*)(ws);             //  2,097,152 B
    unsigned short* MbT   = (unsigned short*)(ws + 2097152);   //  6,291,456 B
    unsigned short* ToepA = (unsigned short*)(ws + 8388608);   // 12,582,912 B
    unsigned short* Zbuf  = (unsigned short*)(ws + 20971520);  // g * 25,165,824 B
    const size_t fixed = 20971520;

    int g = 4, kg = 16;
    auto need = [&](int gg, int kk) {
        return fixed + (size_t)gg * 25165824 + (size_t)gg * (size_t)kk * 524288;
    };
    if (need(4, 16) > ws_size) {
        kg = 12;
        if (need(4, 12) > ws_size) {
            g = 2; kg = 16;
            if (need(2, 16) > ws_size) {
                kg = 12;
                if (need(2, 12) > ws_size) {
                    g = 1; kg = 16;
                    if (need(1, 16) > ws_size) {
                        kg = 12;
                        if (need(1, 12) > ws_size) kg = 6;
                    }
                }
            }
        }
    }
    unsigned short* partial = (unsigned short*)(ws + fixed + (size_t)g * 25165824);

    k_prep_all<<<dim3(4864), dim3(256), 0, stream>>>(x, phi, Mp, Mm, xb, ToepA, MbT);

    for (int b0 = 0; b0 < 4; b0 += g) {
        k_stage1<<<dim3(8, 96, g), dim3(256), 0, stream>>>(xb + (size_t)b0 * 262144, MbT, Zbuf);
        k_stage2<<<dim3(4, 2 * g, kg), dim3(256), 0, stream>>>(Zbuf, ToepA, partial, 48 / kg);
        k_reduce<<<dim3(128, g), dim3(256), 0, stream>>>(partial, out + (size_t)b0 * 262144, kg);
    }
}